// Round 1
// baseline (362.502 us; speedup 1.0000x reference)
//
#include <hip/hip_runtime.h>
#include <hip/hip_bf16.h>
#include <math.h>

#define HH 1024
#define WW 2048
#define HW (HH*WW)
#define KC 32
#define CAP 65536

struct Scratch {
  int ncand;
  int cnt;
  int kRemain;
  unsigned prefix;
  float scale;
  int nvalid;
  float cy[KC];
  float cx[KC];
  unsigned hist[2048];
};

__global__ void k_init(Scratch* sc){
  int t = threadIdx.x;
  if (t==0){ sc->ncand=0; sc->cnt=0; sc->kRemain=0; sc->prefix=0; sc->scale=0.0f; sc->nvalid=0; }
  for (int i=t;i<2048;i+=blockDim.x) sc->hist[i]=0;
}

__global__ void k_collect(const float* __restrict__ heat, unsigned long long* __restrict__ cand, Scratch* sc){
  int i = blockIdx.x*blockDim.x + threadIdx.x;
  if (i >= HW) return;
  float v = heat[i];
  if (v > 0.0f){
    int slot = atomicAdd(&sc->ncand, 1);
    if (slot < CAP){
      unsigned vb = __float_as_uint(v);
      cand[slot] = ((unsigned long long)vb << 32) | (unsigned long long)(unsigned)(~(unsigned)i);
    }
  }
}

// one block: iteratively select 32 maxima (value desc, index asc)
__global__ void k_select(const unsigned long long* __restrict__ cand, Scratch* sc){
  __shared__ unsigned long long red[256];
  __shared__ unsigned long long prevs;
  int t = threadIdx.x;
  int n = sc->ncand; if (n > CAP) n = CAP;
  if (t==0) prevs = ~0ULL;
  __syncthreads();
  int k;
  for (k=0;k<KC;k++){
    unsigned long long prev = prevs;
    unsigned long long best = 0;
    for (int j=t;j<n;j+=256){
      unsigned long long key = cand[j];
      if (key < prev && key > best) best = key;
    }
    red[t]=best; __syncthreads();
    for (int s=128;s>0;s>>=1){ if (t<s && red[t+s]>red[t]) red[t]=red[t+s]; __syncthreads(); }
    unsigned long long b = red[0];
    __syncthreads();
    if (b == 0ULL) break;
    if (t==0){
      unsigned idx = ~(unsigned)(b & 0xFFFFFFFFULL);
      sc->cy[k] = (float)(idx >> 11);
      sc->cx[k] = (float)(idx & 2047u);
      prevs = b;
    }
    __syncthreads();
  }
  if (t==0) sc->nvalid = k;
}

__global__ void k_label(const int* __restrict__ sem, const float* __restrict__ off,
                        const Scratch* __restrict__ sc, float* __restrict__ out){
  __shared__ float scy[KC], scx[KC];
  __shared__ int snv;
  if (threadIdx.x < KC){ scy[threadIdx.x] = sc->cy[threadIdx.x]; scx[threadIdx.x] = sc->cx[threadIdx.x]; }
  if (threadIdx.x == 0) snv = sc->nvalid;
  __syncthreads();
  int i = blockIdx.x*blockDim.x + threadIdx.x;
  if (i>=HW) return;
  int y = i >> 11, x = i & 2047;
  int s = sem[i];
  int nv = snv;
  int lab = s;
  if (s >= 11 && nv > 0){
    float ys = (float)y + off[i];
    float xs = (float)x + off[HW + i];
    float best = INFINITY; int bi = 0;
    for (int k=0;k<nv;k++){
      float dy = ys - scy[k];
      float dx = xs - scx[k];
      float d = dy*dy + dx*dx;
      if (d < best){ best = d; bi = k; }
    }
    lab = s*1000 + bi + 1;
  }
  out[i] = (float)lab;
}

__device__ __forceinline__ void campt(const float* __restrict__ depth, const float* ik,
                                      int xx, int yy, float p[3]){
  float d = depth[yy*WW + xx];
  float fx = (float)xx, fy = (float)yy;
  p[0] = (ik[0]*fx + ik[1]*fy + ik[2]) * d;
  p[1] = (ik[3]*fx + ik[4]*fy + ik[5]) * d;
  p[2] = (ik[6]*fx + ik[7]*fy + ik[8]) * d;
}

__global__ void k_heights(const float* __restrict__ depth, const float* __restrict__ invK,
                          const float* __restrict__ out, unsigned* __restrict__ hbuf, Scratch* sc){
  __shared__ float ik[9];
  __shared__ int blkcnt;
  if (threadIdx.x < 9) ik[threadIdx.x] = invK[threadIdx.x];
  if (threadIdx.x == 0) blkcnt = 0;
  __syncthreads();
  int i = blockIdx.x*blockDim.x + threadIdx.x;
  bool ground = false;
  if (i < HW){
    int y = i >> 11, x = i & 2047;
    float pxp[3], pxm[3], pyp[3], pym[3], pc[3];
    campt(depth, ik, min(x+1, WW-1), y, pxp);
    campt(depth, ik, max(x-1, 0),    y, pxm);
    campt(depth, ik, x, min(y+1, HH-1), pyp);
    campt(depth, ik, x, max(y-1, 0),    pym);
    campt(depth, ik, x, y, pc);
    float vx0 = pxp[0]-pxm[0], vx1 = pxp[1]-pxm[1], vx2 = pxp[2]-pxm[2];
    float vy0 = pyp[0]-pym[0], vy1 = pyp[1]-pym[1], vy2 = pyp[2]-pym[2];
    float n0 = vx1*vy2 - vx2*vy1;
    float n1 = vx2*vy0 - vx0*vy2;
    float n2 = vx0*vy1 - vx1*vy0;
    float nn = sqrtf(n0*n0 + n1*n1 + n2*n2) + 1e-8f;
    float h = fabsf(pc[0]*n0 + pc[1]*n1 + pc[2]*n2) / nn;
    ground = (out[i] == 0.0f);
    hbuf[i] = ground ? __float_as_uint(h) : 0xFFFFFFFFu;
  }
  if (ground) atomicAdd(&blkcnt, 1);
  __syncthreads();
  if (threadIdx.x==0 && blkcnt) atomicAdd(&sc->cnt, blkcnt);
}

template<int PASS>
__global__ void k_hist(const unsigned* __restrict__ hbuf, Scratch* sc){
  __shared__ unsigned h[2048];
  for (int j=threadIdx.x;j<2048;j+=blockDim.x) h[j]=0;
  __syncthreads();
  unsigned pref = sc->prefix;
  for (int i = blockIdx.x*blockDim.x + threadIdx.x; i < HW; i += gridDim.x*blockDim.x){
    unsigned key = hbuf[i];
    if (PASS==0){
      atomicAdd(&h[key>>21], 1u);
    } else if (PASS==1){
      if ((key>>21) == pref) atomicAdd(&h[(key>>10)&2047u], 1u);
    } else {
      if ((key>>10) == pref) atomicAdd(&h[key & 1023u], 1u);
    }
  }
  __syncthreads();
  for (int j=threadIdx.x;j<2048;j+=blockDim.x){ unsigned v=h[j]; if (v) atomicAdd(&sc->hist[j], v); }
}

template<int PASS>
__global__ void k_pick(Scratch* sc, const float* __restrict__ rch){
  int t = threadIdx.x;
  if (t == 0){
    int k;
    if (PASS==0){
      int c = sc->cnt;
      k = (c > 0) ? ((c-1)>>1) : 0;
    } else {
      k = sc->kRemain;
    }
    int nb = (PASS==2) ? 1024 : 2048;
    int b = 0;
    for (; b < nb-1; b++){
      unsigned hv = sc->hist[b];
      if ((unsigned)k < hv) break;
      k -= (int)hv;
    }
    if (PASS==0){
      sc->prefix = (unsigned)b;
    } else if (PASS==1){
      sc->prefix = (sc->prefix << 11) | (unsigned)b;
    } else {
      unsigned key = (sc->prefix << 10) | (unsigned)b;
      float hmed = __uint_as_float(key);
      sc->scale = (sc->cnt > 0) ? (rch[0] / hmed) : 0.0f;
    }
    sc->kRemain = k;
  }
  __syncthreads();
  for (int j=t;j<2048;j+=blockDim.x) sc->hist[j]=0;
}

__global__ void k_final(const float* __restrict__ depth, const float* __restrict__ invK,
                        const Scratch* __restrict__ sc, float* __restrict__ out){
  __shared__ float ik[9];
  __shared__ float sscale;
  if (threadIdx.x < 9) ik[threadIdx.x] = invK[threadIdx.x];
  if (threadIdx.x == 0) sscale = sc->scale;
  __syncthreads();
  int i = blockIdx.x*blockDim.x + threadIdx.x;
  if (i >= HW) return;
  int y = i>>11, x = i & 2047;
  float lab = out[i];
  float d = depth[i];
  float s = sscale;
  float fx=(float)x, fy=(float)y;
  float p0 = (ik[0]*fx+ik[1]*fy+ik[2]) * d * s;
  float p1 = (ik[3]*fx+ik[4]*fy+ik[5]) * d * s;
  float p2 = (ik[6]*fx+ik[7]*fy+ik[8]) * d * s;
  bool filt = (lab == 10.0f) || (lab == 19.0f);
  out[HW + i] = filt ? 0.0f : d*s;
  ((float4*)(out + (size_t)2*HW))[i] = make_float4(p0, p1, p2, lab);
}

extern "C" void kernel_launch(void* const* d_in, const int* in_sizes, int n_in,
                              void* d_out, int out_size, void* d_ws, size_t ws_size,
                              hipStream_t stream){
  const int*   sem   = (const int*)d_in[0];
  const float* heat  = (const float*)d_in[1];
  const float* off   = (const float*)d_in[2];
  const float* depth = (const float*)d_in[3];
  const float* invK  = (const float*)d_in[4];
  const float* rch   = (const float*)d_in[5];
  float* out = (float*)d_out;

  unsigned* hbuf = (unsigned*)d_ws;
  unsigned long long* cand = (unsigned long long*)((char*)d_ws + (size_t)HW*4);
  Scratch* sc = (Scratch*)((char*)d_ws + (size_t)HW*4 + (size_t)CAP*8);

  const int blk = 256;
  const int grid = (HW + blk - 1)/blk;

  k_init<<<1, 256, 0, stream>>>(sc);
  k_collect<<<grid, blk, 0, stream>>>(heat, cand, sc);
  k_select<<<1, 256, 0, stream>>>(cand, sc);
  k_label<<<grid, blk, 0, stream>>>(sem, off, sc, out);
  k_heights<<<grid, blk, 0, stream>>>(depth, invK, out, hbuf, sc);
  k_hist<0><<<1024, 256, 0, stream>>>(hbuf, sc);
  k_pick<0><<<1, 256, 0, stream>>>(sc, rch);
  k_hist<1><<<1024, 256, 0, stream>>>(hbuf, sc);
  k_pick<1><<<1, 256, 0, stream>>>(sc, rch);
  k_hist<2><<<1024, 256, 0, stream>>>(hbuf, sc);
  k_pick<2><<<1, 256, 0, stream>>>(sc, rch);
  k_final<<<grid, blk, 0, stream>>>(depth, invK, sc, out);
}

// Round 2
// 249.723 us; speedup vs baseline: 1.4516x; 1.4516x over previous
//
#include <hip/hip_runtime.h>
#include <math.h>

#define HH 1024
#define WW 2048
#define HW (HH*WW)
#define KC 32
#define CAP 65536
#define LCAP 6144

typedef unsigned long long u64;

struct Scratch {
  int ncand, cnt, kRemain, nvalid;
  unsigned prefix;
  float scale;
  float cy[KC], cx[KC];
  unsigned hist[2048];
};

__global__ void k_collect(const float* __restrict__ heat, u64* __restrict__ cand, Scratch* sc){
  int i4 = blockIdx.x*blockDim.x + threadIdx.x;
  float4 v = ((const float4*)heat)[i4];
  int p = i4<<2;
  float vv[4] = {v.x, v.y, v.z, v.w};
  #pragma unroll
  for (int j=0;j<4;j++){
    if (vv[j] > 0.0f){
      int slot = atomicAdd(&sc->ncand, 1);
      if (slot < CAP)
        cand[slot] = ((u64)__float_as_uint(vv[j])<<32) | (u64)(unsigned)(~(unsigned)(p+j));
    }
  }
}

// one block: iteratively select up to 32 maxima (value desc, index asc)
__global__ void k_select(const u64* __restrict__ cand, Scratch* sc){
  __shared__ u64 lcache[LCAP];
  __shared__ u64 wred[4];
  __shared__ u64 prevs;
  int t = threadIdx.x;
  int n = sc->ncand; if (n > CAP) n = CAP;
  int nl = n < LCAP ? n : LCAP;
  for (int j=t;j<nl;j+=256) lcache[j] = cand[j];
  if (t==0) prevs = ~0ULL;
  __syncthreads();
  int k;
  for (k=0;k<KC;k++){
    u64 prev = prevs;
    u64 best = 0;
    for (int j=t;j<nl;j+=256){ u64 key = lcache[j]; if (key < prev && key > best) best = key; }
    for (int j=LCAP+t;j<n;j+=256){ u64 key = cand[j]; if (key < prev && key > best) best = key; }
    #pragma unroll
    for (int m=32;m>=1;m>>=1){ u64 o = __shfl_xor(best, m); if (o > best) best = o; }
    if ((t&63)==0) wred[t>>6] = best;
    __syncthreads();
    if (t==0){
      u64 b = wred[0];
      #pragma unroll
      for (int w=1;w<4;w++) if (wred[w] > b) b = wred[w];
      if (b){
        unsigned idx = ~(unsigned)(b & 0xFFFFFFFFULL);
        sc->cy[k] = (float)(idx >> 11);
        sc->cx[k] = (float)(idx & 2047u);
      }
      prevs = b;
    }
    __syncthreads();
    if (prevs == 0ULL) break;
  }
  if (t==0) sc->nvalid = k;
}

// fused: instance labels + surface-normal heights + ground compaction (4 px/thread)
__global__ __launch_bounds__(256) void k_main(const int* __restrict__ sem, const float* __restrict__ off,
    const float* __restrict__ depth, const float* __restrict__ invK,
    Scratch* __restrict__ sc, float* __restrict__ out, unsigned* __restrict__ compact){
  __shared__ float scy[KC], scx[KC];
  __shared__ int snv;
  __shared__ unsigned lcnt, gbase;
  int t = threadIdx.x;
  if (t < KC){ scy[t] = sc->cy[t]; scx[t] = sc->cx[t]; }
  if (t == 0){ snv = sc->nvalid; lcnt = 0u; }
  __syncthreads();

  int i4 = blockIdx.x*256 + t;
  int p = i4<<2;
  int y = p>>11, x = p&2047;
  int row = y<<11;

  // issue all loads up-front, independent
  int4   s4 = ((const int4*)sem)[i4];
  float4 oy = ((const float4*)off)[i4];
  float4 ox = ((const float4*)(off+HW))[i4];
  float4 dc = ((const float4*)depth)[i4];
  float  dl = depth[row + (x>0 ? x-1 : 0)];
  float  dr = depth[row + (x+4<WW ? x+4 : WW-1)];
  float4 du = ((const float4*)(depth + (y>0     ? row-WW : row)))[x>>2];
  float4 dd = ((const float4*)(depth + (y<HH-1  ? row+WW : row)))[x>>2];

  float ik0=invK[0],ik1=invK[1],ik2=invK[2];
  float ik3=invK[3],ik4=invK[4],ik5=invK[5];
  float ik6=invK[6],ik7=invK[7],ik8=invK[8];

  int   ss[4]  = {s4.x, s4.y, s4.z, s4.w};
  float dcv[4] = {dc.x, dc.y, dc.z, dc.w};
  float duv[4] = {du.x, du.y, du.z, du.w};
  float ddv[4] = {dd.x, dd.y, dd.z, dd.w};
  float oyv[4] = {oy.x, oy.y, oy.z, oy.w};
  float oxv[4] = {ox.x, ox.y, ox.z, ox.w};

  float fy = (float)y;
  // --- instance grouping ---
  float ys_[4], xs_[4], best[4]; int bi[4];
  #pragma unroll
  for (int j=0;j<4;j++){ ys_[j] = fy + oyv[j]; xs_[j] = (float)(x+j) + oxv[j]; best[j] = INFINITY; bi[j] = 0; }
  int nv = snv;
  for (int k=0;k<nv;k++){
    float cyk = scy[k], cxk = scx[k];
    #pragma unroll
    for (int j=0;j<4;j++){
      float dyv = ys_[j]-cyk, dxv = xs_[j]-cxk;
      float d = dyv*dyv + dxv*dxv;
      if (d < best[j]){ best[j] = d; bi[j] = k; }
    }
  }
  float lab[4];
  #pragma unroll
  for (int j=0;j<4;j++){
    int s = ss[j];
    lab[j] = (s >= 11 && nv > 0) ? (float)(s*1000 + bi[j] + 1) : (float)s;
  }
  ((float4*)out)[i4] = make_float4(lab[0], lab[1], lab[2], lab[3]);

  // --- surface-normal heights ---
  float a0 = ik1*fy+ik2, a1 = ik4*fy+ik5, a2 = ik7*fy+ik8;
  float fyu = (y>0)    ? fy-1.0f : fy;
  float fyd = (y<HH-1) ? fy+1.0f : fy;
  float u0 = ik1*fyu+ik2, u1 = ik4*fyu+ik5, u2 = ik7*fyu+ik8;
  float w0 = ik1*fyd+ik2, w1 = ik4*fyd+ik5, w2 = ik7*fyd+ik8;
  float dxmv[4] = {dl, dcv[0], dcv[1], dcv[2]};
  float dxpv[4] = {dcv[1], dcv[2], dcv[3], dr};
  float h[4];
  #pragma unroll
  for (int j=0;j<4;j++){
    float fx  = (float)(x+j);
    float fxm = (x+j>0)     ? fx-1.0f : fx;
    float fxp = (x+j<WW-1)  ? fx+1.0f : fx;
    float pc0=(ik0*fx +a0)*dcv[j],  pc1=(ik3*fx +a1)*dcv[j],  pc2=(ik6*fx +a2)*dcv[j];
    float pm0=(ik0*fxm+a0)*dxmv[j], pm1=(ik3*fxm+a1)*dxmv[j], pm2=(ik6*fxm+a2)*dxmv[j];
    float pp0=(ik0*fxp+a0)*dxpv[j], pp1=(ik3*fxp+a1)*dxpv[j], pp2=(ik6*fxp+a2)*dxpv[j];
    float pu0=(ik0*fx +u0)*duv[j],  pu1=(ik3*fx +u1)*duv[j],  pu2=(ik6*fx +u2)*duv[j];
    float pd0=(ik0*fx +w0)*ddv[j],  pd1=(ik3*fx +w1)*ddv[j],  pd2=(ik6*fx +w2)*ddv[j];
    float vx0=pp0-pm0, vx1=pp1-pm1, vx2=pp2-pm2;
    float vy0=pd0-pu0, vy1=pd1-pu1, vy2=pd2-pu2;
    float n0=vx1*vy2-vx2*vy1, n1=vx2*vy0-vx0*vy2, n2=vx0*vy1-vx1*vy0;
    float nn = sqrtf(n0*n0+n1*n1+n2*n2) + 1e-8f;
    h[j] = fabsf(pc0*n0+pc1*n1+pc2*n2) / nn;
  }

  // --- compact ground heights ---
  unsigned m0 = (ss[0]==0), m1 = (ss[1]==0), m2 = (ss[2]==0), m3 = (ss[3]==0);
  unsigned ng = m0+m1+m2+m3;
  unsigned loff = 0;
  if (ng) loff = atomicAdd(&lcnt, ng);
  __syncthreads();
  if (t==0 && lcnt) gbase = atomicAdd((unsigned*)&sc->cnt, lcnt);
  __syncthreads();
  if (ng){
    unsigned base = gbase + loff, o = 0;
    if (m0){ compact[base+o] = __float_as_uint(h[0]); o++; }
    if (m1){ compact[base+o] = __float_as_uint(h[1]); o++; }
    if (m2){ compact[base+o] = __float_as_uint(h[2]); o++; }
    if (m3){ compact[base+o] = __float_as_uint(h[3]); }
  }
}

template<int PASS>
__global__ void k_hist(const unsigned* __restrict__ compact, Scratch* sc){
  __shared__ unsigned hsh[2048];
  for (int j=threadIdx.x;j<2048;j+=256) hsh[j]=0;
  __syncthreads();
  int n = sc->cnt;
  unsigned pref = sc->prefix;
  for (int i = blockIdx.x*256 + threadIdx.x; i < n; i += gridDim.x*256){
    unsigned key = compact[i];
    if (PASS==0)      atomicAdd(&hsh[key>>21], 1u);
    else if (PASS==1){ if ((key>>21) == pref) atomicAdd(&hsh[(key>>10)&2047u], 1u); }
    else             { if ((key>>10) == pref) atomicAdd(&hsh[key & 1023u], 1u); }
  }
  __syncthreads();
  for (int j=threadIdx.x;j<2048;j+=256){ unsigned v=hsh[j]; if (v) atomicAdd(&sc->hist[j], v); }
}

template<int PASS>
__global__ void k_pick(Scratch* sc, const float* __restrict__ rch){
  int t = threadIdx.x;
  if (t == 0){
    int k;
    if (PASS==0){
      int c = sc->cnt;
      k = (c > 0) ? ((c-1)>>1) : 0;
    } else {
      k = sc->kRemain;
    }
    int nb = (PASS==2) ? 1024 : 2048;
    int b = 0;
    for (; b < nb-1; b++){
      unsigned hv = sc->hist[b];
      if ((unsigned)k < hv) break;
      k -= (int)hv;
    }
    if (PASS==0){
      sc->prefix = (unsigned)b;
    } else if (PASS==1){
      sc->prefix = (sc->prefix << 11) | (unsigned)b;
    } else {
      unsigned key = (sc->prefix << 10) | (unsigned)b;
      float hmed = __uint_as_float(key);
      sc->scale = (sc->cnt > 0) ? (rch[0] / hmed) : 0.0f;
    }
    sc->kRemain = k;
  }
  __syncthreads();
  for (int j=t;j<2048;j+=blockDim.x) sc->hist[j]=0;
}

__global__ __launch_bounds__(256) void k_final(const float* __restrict__ depth, const float* __restrict__ invK,
    const Scratch* __restrict__ sc, float* __restrict__ out){
  int i4 = blockIdx.x*256 + threadIdx.x;
  int p = i4<<2;
  int y = p>>11, x = p&2047;
  float4 l4 = ((const float4*)out)[i4];
  float4 dc = ((const float4*)depth)[i4];
  float s = sc->scale;
  float ik0=invK[0],ik1=invK[1],ik2=invK[2];
  float ik3=invK[3],ik4=invK[4],ik5=invK[5];
  float ik6=invK[6],ik7=invK[7],ik8=invK[8];
  float fy = (float)y;
  float a0 = ik1*fy+ik2, a1 = ik4*fy+ik5, a2 = ik7*fy+ik8;
  float labv[4] = {l4.x, l4.y, l4.z, l4.w};
  float dv[4]   = {dc.x, dc.y, dc.z, dc.w};
  float depo[4];
  float4* cam = (float4*)(out + (size_t)2*HW);
  #pragma unroll
  for (int j=0;j<4;j++){
    float fx = (float)(x+j);
    float ds = dv[j]*s;
    float p0 = (ik0*fx+a0)*ds, p1 = (ik3*fx+a1)*ds, p2 = (ik6*fx+a2)*ds;
    bool filt = (labv[j]==10.0f) || (labv[j]==19.0f);
    depo[j] = filt ? 0.0f : ds;
    cam[p+j] = make_float4(p0, p1, p2, labv[j]);
  }
  ((float4*)(out+HW))[i4] = make_float4(depo[0], depo[1], depo[2], depo[3]);
}

extern "C" void kernel_launch(void* const* d_in, const int* in_sizes, int n_in,
                              void* d_out, int out_size, void* d_ws, size_t ws_size,
                              hipStream_t stream){
  const int*   sem   = (const int*)d_in[0];
  const float* heat  = (const float*)d_in[1];
  const float* off   = (const float*)d_in[2];
  const float* depth = (const float*)d_in[3];
  const float* invK  = (const float*)d_in[4];
  const float* rch   = (const float*)d_in[5];
  float* out = (float*)d_out;

  unsigned* compact = (unsigned*)d_ws;                                   // HW*4 bytes cap
  u64* cand = (u64*)((char*)d_ws + (size_t)HW*4);                        // CAP*8 bytes
  Scratch* sc = (Scratch*)((char*)d_ws + (size_t)HW*4 + (size_t)CAP*8);

  const int blk = 256;
  const int grid4 = HW/4/blk;   // 2048

  hipMemsetAsync(sc, 0, sizeof(Scratch), stream);
  k_collect<<<grid4, blk, 0, stream>>>(heat, cand, sc);
  k_select<<<1, blk, 0, stream>>>(cand, sc);
  k_main<<<grid4, blk, 0, stream>>>(sem, off, depth, invK, sc, out, compact);
  k_hist<0><<<128, blk, 0, stream>>>(compact, sc);
  k_pick<0><<<1, blk, 0, stream>>>(sc, rch);
  k_hist<1><<<128, blk, 0, stream>>>(compact, sc);
  k_pick<1><<<1, blk, 0, stream>>>(sc, rch);
  k_hist<2><<<128, blk, 0, stream>>>(compact, sc);
  k_pick<2><<<1, blk, 0, stream>>>(sc, rch);
  k_final<<<grid4, blk, 0, stream>>>(depth, invK, sc, out);
}

// Round 3
// 147.350 us; speedup vs baseline: 2.4601x; 1.6948x over previous
//
#include <hip/hip_runtime.h>
#include <math.h>

#define HH 1024
#define WW 2048
#define HW (HH*WW)
#define KC 32
#define CAP 65536
#define LCAP 6144
#define SENT 0xFFFFFFFFu
#define BIAS 16777216.0f  /* 2^24 */

typedef unsigned long long u64;

struct Scratch {              // hist first: 16B-aligned for uint4 access
  unsigned hist[2048];
  int ncand, cnt, kRemain, nvalid;
  unsigned prefix;
  float scale;
  float ck[KC], m2cy[KC], m2cx[KC];
};

__global__ void k_collect(const float* __restrict__ heat, u64* __restrict__ cand, Scratch* sc){
  int i4 = blockIdx.x*blockDim.x + threadIdx.x;
  float4 v = ((const float4*)heat)[i4];
  int p = i4<<2;
  float vv[4] = {v.x, v.y, v.z, v.w};
  #pragma unroll
  for (int j=0;j<4;j++){
    if (vv[j] > 0.0f){
      int slot = atomicAdd(&sc->ncand, 1);
      if (slot < CAP)
        cand[slot] = ((u64)__float_as_uint(vv[j])<<32) | (u64)(unsigned)(~(unsigned)(p+j));
    }
  }
}

// one block: iteratively select up to 32 maxima (value desc, index asc)
__global__ void k_select(const u64* __restrict__ cand, Scratch* sc){
  __shared__ u64 lcache[LCAP];
  __shared__ u64 wred[4];
  __shared__ u64 prevs;
  int t = threadIdx.x;
  int n = sc->ncand; if (n > CAP) n = CAP;
  int nl = n < LCAP ? n : LCAP;
  for (int j=t;j<nl;j+=256) lcache[j] = cand[j];
  if (t==0) prevs = ~0ULL;
  __syncthreads();
  int k;
  for (k=0;k<KC;k++){
    u64 prev = prevs;
    u64 best = 0;
    for (int j=t;j<nl;j+=256){ u64 key = lcache[j]; if (key < prev && key > best) best = key; }
    for (int j=LCAP+t;j<n;j+=256){ u64 key = cand[j]; if (key < prev && key > best) best = key; }
    #pragma unroll
    for (int m=32;m>=1;m>>=1){ u64 o = __shfl_xor(best, m); if (o > best) best = o; }
    if ((t&63)==0) wred[t>>6] = best;
    __syncthreads();
    if (t==0){
      u64 b = wred[0];
      #pragma unroll
      for (int w=1;w<4;w++) if (wred[w] > b) b = wred[w];
      if (b){
        unsigned idx = ~(unsigned)(b & 0xFFFFFFFFULL);
        float cy = (float)(idx >> 11), cx = (float)(idx & 2047u);
        sc->ck[k]   = cy*cy + cx*cx + BIAS;
        sc->m2cy[k] = -2.0f*cy;
        sc->m2cx[k] = -2.0f*cx;
      }
      prevs = b;
    }
    __syncthreads();
    if (prevs == 0ULL) break;
  }
  if (t==0) sc->nvalid = k;
}

// fused: instance labels + surface-normal heights (4 px/thread, no atomics/barriers)
__global__ __launch_bounds__(256) void k_main(const int* __restrict__ sem, const float* __restrict__ off,
    const float* __restrict__ depth, const float* __restrict__ invK,
    const Scratch* __restrict__ sc, float* __restrict__ out, unsigned* __restrict__ hbuf){
  __shared__ float sck[KC], smy[KC], smx[KC];
  __shared__ int snv;
  int t = threadIdx.x;
  if (t < KC){ sck[t]=sc->ck[t]; smy[t]=sc->m2cy[t]; smx[t]=sc->m2cx[t]; }
  if (t == 0) snv = sc->nvalid;
  __syncthreads();

  int i4 = blockIdx.x*256 + t;
  int p = i4<<2;
  int y = p>>11, x = p&2047;
  int row = y<<11;

  // issue all loads up-front, independent
  int4   s4 = ((const int4*)sem)[i4];
  float4 oy = ((const float4*)off)[i4];
  float4 ox = ((const float4*)(off+HW))[i4];
  float4 dc = ((const float4*)depth)[i4];
  float  dl = depth[row + (x>0 ? x-1 : 0)];
  float  dr = depth[row + (x+4<WW ? x+4 : WW-1)];
  float4 du = ((const float4*)(depth + (y>0     ? row-WW : row)))[x>>2];
  float4 dd = ((const float4*)(depth + (y<HH-1  ? row+WW : row)))[x>>2];

  float ik0=invK[0],ik1=invK[1],ik2=invK[2];
  float ik3=invK[3],ik4=invK[4],ik5=invK[5];
  float ik6=invK[6],ik7=invK[7],ik8=invK[8];

  int   ss[4]  = {s4.x, s4.y, s4.z, s4.w};
  float dcv[4] = {dc.x, dc.y, dc.z, dc.w};
  float duv[4] = {du.x, du.y, du.z, du.w};
  float ddv[4] = {dd.x, dd.y, dd.z, dd.w};
  float oyv[4] = {oy.x, oy.y, oy.z, oy.w};
  float oxv[4] = {ox.x, ox.y, ox.z, ox.w};

  float fy = (float)y;
  // --- instance grouping: d2-argmin via 2fma + sortable-uint min ---
  float ys_[4], xs_[4];
  unsigned ub[4] = {SENT, SENT, SENT, SENT};
  #pragma unroll
  for (int j=0;j<4;j++){ ys_[j] = fy + oyv[j]; xs_[j] = (float)(x+j) + oxv[j]; }
  int nv = snv;
  for (int k=0;k<nv;k++){
    float ckk = sck[k], my = smy[k], mx = smx[k];
    #pragma unroll
    for (int j=0;j<4;j++){
      float tt = fmaf(ys_[j], my, ckk);
      tt = fmaf(xs_[j], mx, tt);
      unsigned u = (__float_as_uint(tt) & ~31u) | (unsigned)k;
      ub[j] = u < ub[j] ? u : ub[j];
    }
  }
  float lab[4];
  #pragma unroll
  for (int j=0;j<4;j++){
    int s = ss[j];
    lab[j] = (s >= 11 && nv > 0) ? (float)(s*1000 + (int)(ub[j]&31u) + 1) : (float)s;
  }
  ((float4*)out)[i4] = make_float4(lab[0], lab[1], lab[2], lab[3]);

  // --- surface-normal heights ---
  float a0 = ik1*fy+ik2, a1 = ik4*fy+ik5, a2 = ik7*fy+ik8;
  float fyu = (y>0)    ? fy-1.0f : fy;
  float fyd = (y<HH-1) ? fy+1.0f : fy;
  float u0 = ik1*fyu+ik2, u1 = ik4*fyu+ik5, u2 = ik7*fyu+ik8;
  float w0 = ik1*fyd+ik2, w1 = ik4*fyd+ik5, w2 = ik7*fyd+ik8;
  float dxmv[4] = {dl, dcv[0], dcv[1], dcv[2]};
  float dxpv[4] = {dcv[1], dcv[2], dcv[3], dr};
  unsigned hk[4];
  #pragma unroll
  for (int j=0;j<4;j++){
    float fx  = (float)(x+j);
    float fxm = (x+j>0)     ? fx-1.0f : fx;
    float fxp = (x+j<WW-1)  ? fx+1.0f : fx;
    float pc0=(ik0*fx +a0)*dcv[j],  pc1=(ik3*fx +a1)*dcv[j],  pc2=(ik6*fx +a2)*dcv[j];
    float pm0=(ik0*fxm+a0)*dxmv[j], pm1=(ik3*fxm+a1)*dxmv[j], pm2=(ik6*fxm+a2)*dxmv[j];
    float pp0=(ik0*fxp+a0)*dxpv[j], pp1=(ik3*fxp+a1)*dxpv[j], pp2=(ik6*fxp+a2)*dxpv[j];
    float pu0=(ik0*fx +u0)*duv[j],  pu1=(ik3*fx +u1)*duv[j],  pu2=(ik6*fx +u2)*duv[j];
    float pd0=(ik0*fx +w0)*ddv[j],  pd1=(ik3*fx +w1)*ddv[j],  pd2=(ik6*fx +w2)*ddv[j];
    float vx0=pp0-pm0, vx1=pp1-pm1, vx2=pp2-pm2;
    float vy0=pd0-pu0, vy1=pd1-pu1, vy2=pd2-pu2;
    float n0=vx1*vy2-vx2*vy1, n1=vx2*vy0-vx0*vy2, n2=vx0*vy1-vx1*vy0;
    float nn = sqrtf(n0*n0+n1*n1+n2*n2) + 1e-8f;
    float h = fabsf(pc0*n0+pc1*n1+pc2*n2) / nn;
    hk[j] = (ss[j]==0) ? __float_as_uint(h) : SENT;
  }
  ((uint4*)hbuf)[i4] = make_uint4(hk[0], hk[1], hk[2], hk[3]);
}

template<int PASS>
__global__ void k_hist(const unsigned* __restrict__ hbuf, Scratch* sc){
  __shared__ unsigned hsh[2048];
  for (int j=threadIdx.x;j<2048;j+=256) hsh[j]=0;
  __syncthreads();
  unsigned pref = sc->prefix;
  for (int i = blockIdx.x*256 + threadIdx.x; i < HW/4; i += gridDim.x*256){
    uint4 kv = ((const uint4*)hbuf)[i];
    unsigned ks[4] = {kv.x, kv.y, kv.z, kv.w};
    #pragma unroll
    for (int j=0;j<4;j++){
      unsigned key = ks[j];
      if (key == SENT) continue;
      if (PASS==0)      atomicAdd(&hsh[key>>21], 1u);
      else if (PASS==1){ if ((key>>21) == pref) atomicAdd(&hsh[(key>>10)&2047u], 1u); }
      else             { if ((key>>10) == pref) atomicAdd(&hsh[key & 1023u], 1u); }
    }
  }
  __syncthreads();
  for (int j=threadIdx.x;j<2048;j+=256){ unsigned v=hsh[j]; if (v) atomicAdd(&sc->hist[j], v); }
}

// parallel k-th-bucket selection: 256 threads x 8 bins, wave scan + LDS scan
template<int PASS>
__global__ void k_pick(Scratch* sc, const float* __restrict__ rch){
  __shared__ unsigned wsum[4];
  int t = threadIdx.x;
  uint4 va = ((const uint4*)sc->hist)[2*t];
  uint4 vb = ((const uint4*)sc->hist)[2*t+1];
  unsigned v[8] = {va.x,va.y,va.z,va.w,vb.x,vb.y,vb.z,vb.w};
  unsigned s = 0;
  #pragma unroll
  for (int j=0;j<8;j++) s += v[j];
  unsigned incl = s;
  #pragma unroll
  for (int d=1; d<64; d<<=1){ unsigned o = __shfl_up(incl, d); if ((t&63) >= d) incl += o; }
  unsigned excl = incl - s;
  if ((t&63)==63) wsum[t>>6] = incl;
  __syncthreads();
  unsigned woff = 0, total = 0;
  #pragma unroll
  for (int w=0;w<4;w++){ unsigned xw = wsum[w]; if (w < (t>>6)) woff += xw; total += xw; }
  unsigned pre = woff + excl;
  int k;
  if (PASS==0){
    int c = (int)total;
    if (t==0) sc->cnt = c;
    k = (c > 0) ? ((c-1)>>1) : 0;
  } else {
    k = sc->kRemain;
  }
  if ((unsigned)k >= pre && (unsigned)k < pre + s){
    unsigned kr = (unsigned)k - pre;
    int b_ = 0;
    #pragma unroll
    for (int j=0;j<8;j++){
      if (kr < v[j]){ b_ = t*8+j; break; }
      kr -= v[j];
    }
    sc->kRemain = (int)kr;
    if (PASS==0)      sc->prefix = (unsigned)b_;
    else if (PASS==1) sc->prefix = (sc->prefix << 11) | (unsigned)b_;
    else {
      unsigned key = (sc->prefix << 10) | (unsigned)b_;
      sc->scale = (sc->cnt > 0) ? (rch[0] / __uint_as_float(key)) : 0.0f;
    }
  }
  __syncthreads();
  ((uint4*)sc->hist)[2*t]   = make_uint4(0,0,0,0);
  ((uint4*)sc->hist)[2*t+1] = make_uint4(0,0,0,0);
}

__global__ __launch_bounds__(256) void k_final(const float* __restrict__ depth, const float* __restrict__ invK,
    const Scratch* __restrict__ sc, float* __restrict__ out){
  int i4 = blockIdx.x*256 + threadIdx.x;
  int p = i4<<2;
  int y = p>>11, x = p&2047;
  float4 l4 = ((const float4*)out)[i4];
  float4 dc = ((const float4*)depth)[i4];
  float s = sc->scale;
  float ik0=invK[0],ik1=invK[1],ik2=invK[2];
  float ik3=invK[3],ik4=invK[4],ik5=invK[5];
  float ik6=invK[6],ik7=invK[7],ik8=invK[8];
  float fy = (float)y;
  float a0 = ik1*fy+ik2, a1 = ik4*fy+ik5, a2 = ik7*fy+ik8;
  float labv[4] = {l4.x, l4.y, l4.z, l4.w};
  float dv[4]   = {dc.x, dc.y, dc.z, dc.w};
  float depo[4];
  float4* cam = (float4*)(out + (size_t)2*HW);
  #pragma unroll
  for (int j=0;j<4;j++){
    float fx = (float)(x+j);
    float ds = dv[j]*s;
    float p0 = (ik0*fx+a0)*ds, p1 = (ik3*fx+a1)*ds, p2 = (ik6*fx+a2)*ds;
    bool filt = (labv[j]==10.0f) || (labv[j]==19.0f);
    depo[j] = filt ? 0.0f : ds;
    cam[p+j] = make_float4(p0, p1, p2, labv[j]);
  }
  ((float4*)(out+HW))[i4] = make_float4(depo[0], depo[1], depo[2], depo[3]);
}

extern "C" void kernel_launch(void* const* d_in, const int* in_sizes, int n_in,
                              void* d_out, int out_size, void* d_ws, size_t ws_size,
                              hipStream_t stream){
  const int*   sem   = (const int*)d_in[0];
  const float* heat  = (const float*)d_in[1];
  const float* off   = (const float*)d_in[2];
  const float* depth = (const float*)d_in[3];
  const float* invK  = (const float*)d_in[4];
  const float* rch   = (const float*)d_in[5];
  float* out = (float*)d_out;

  unsigned* hbuf = (unsigned*)d_ws;                                      // HW*4 bytes
  u64* cand = (u64*)((char*)d_ws + (size_t)HW*4);                        // CAP*8 bytes
  Scratch* sc = (Scratch*)((char*)d_ws + (size_t)HW*4 + (size_t)CAP*8);

  const int blk = 256;
  const int grid4 = HW/4/blk;   // 2048

  hipMemsetAsync(sc, 0, sizeof(Scratch), stream);
  k_collect<<<grid4, blk, 0, stream>>>(heat, cand, sc);
  k_select<<<1, blk, 0, stream>>>(cand, sc);
  k_main<<<grid4, blk, 0, stream>>>(sem, off, depth, invK, sc, out, hbuf);
  k_hist<0><<<512, blk, 0, stream>>>(hbuf, sc);
  k_pick<0><<<1, blk, 0, stream>>>(sc, rch);
  k_hist<1><<<512, blk, 0, stream>>>(hbuf, sc);
  k_pick<1><<<1, blk, 0, stream>>>(sc, rch);
  k_hist<2><<<512, blk, 0, stream>>>(hbuf, sc);
  k_pick<2><<<1, blk, 0, stream>>>(sc, rch);
  k_final<<<grid4, blk, 0, stream>>>(depth, invK, sc, out);
}

// Round 4
// 141.997 us; speedup vs baseline: 2.5529x; 1.0377x over previous
//
#include <hip/hip_runtime.h>
#include <math.h>

#define HH 1024
#define WW 2048
#define HW (HH*WW)
#define KC 32
#define CAP 65536
#define SENT 0xFFFFFFFFu
#define BIAS 16777216.0f  /* 2^24 */

typedef unsigned long long u64;

struct Scratch {              // hist first: 16B-aligned for uint4 access
  unsigned hist[2048];
  int ncand, cnt, kRemain, nvalid;
  unsigned prefix;
  float scale;
  float ck[KC], m2cy[KC], m2cx[KC];
};

__global__ void k_collect(const float* __restrict__ heat, u64* __restrict__ cand, Scratch* sc){
  int i4 = blockIdx.x*blockDim.x + threadIdx.x;
  float4 v = ((const float4*)heat)[i4];
  int p = i4<<2;
  float vv[4] = {v.x, v.y, v.z, v.w};
  #pragma unroll
  for (int j=0;j<4;j++){
    if (vv[j] > 0.0f){
      int slot = atomicAdd(&sc->ncand, 1);
      if (slot < CAP)
        cand[slot] = ((u64)__float_as_uint(vv[j])<<32) | (u64)(unsigned)(~(unsigned)(p+j));
    }
  }
}

// 1024 threads = 16 waves. Phase 1: each wave extracts its chunk's top-32
// (candidates register-resident, shfl-only, no barriers). Phase 2: one wave
// does a 16-way merge of the sorted lists via per-lane head pointers.
__global__ __launch_bounds__(1024) void k_select(const u64* __restrict__ cand, Scratch* sc){
  __shared__ u64 loc[16*KC];
  int t = threadIdx.x;
  int lane = t & 63;
  int w = t >> 6;
  int n = sc->ncand; if (n > CAP) n = CAP;

  if (t < 16*KC) loc[t] = 0ULL;
  __syncthreads();

  int chunk = (n + 15) >> 4;
  int start = w * chunk;
  int end   = min(n, start + chunk);

  // register-resident candidates (covers chunk <= 512, i.e. n <= 8192)
  u64 rv[8];
  #pragma unroll
  for (int i=0;i<8;i++){
    int idx = start + lane + (i<<6);
    rv[i] = (idx < end) ? cand[idx] : 0ULL;
  }
  bool over = (end - start) > 512;

  u64 prev = ~0ULL;
  for (int r=0;r<KC;r++){
    u64 best = 0ULL;
    #pragma unroll
    for (int i=0;i<8;i++){ u64 key = rv[i]; if (key < prev && key > best) best = key; }
    if (over){
      for (int idx = start + 512 + lane; idx < end; idx += 64){
        u64 key = cand[idx]; if (key < prev && key > best) best = key;
      }
    }
    #pragma unroll
    for (int m=32;m>=1;m>>=1){ u64 o = __shfl_xor(best, m); if (o > best) best = o; }
    if (best == 0ULL) break;
    if (lane == 0) loc[w*KC + r] = best;
    prev = best;
  }
  __syncthreads();

  // Phase 2: wave 0 merges 16 descending lists of 32
  if (w == 0){
    int ptr = lane * KC;
    int lim = ptr + KC;
    int k = 0;
    u64 prevm = ~0ULL;   // unused filter; lists already < prev chain
    for (int r=0;r<KC;r++){
      u64 key = (lane < 16 && ptr < lim) ? loc[ptr] : 0ULL;
      u64 mx = key;
      #pragma unroll
      for (int m=32;m>=1;m>>=1){ u64 o = __shfl_xor(mx, m); if (o > mx) mx = o; }
      if (mx == 0ULL) break;
      u64 ball = __ballot(key == mx);
      int winner = __ffsll((long long)ball) - 1;
      if (lane == winner) ptr++;
      if (lane == 0){
        unsigned idx = ~(unsigned)(mx & 0xFFFFFFFFULL);
        float cy = (float)(idx >> 11), cx = (float)(idx & 2047u);
        sc->ck[r]   = cy*cy + cx*cx + BIAS;
        sc->m2cy[r] = -2.0f*cy;
        sc->m2cx[r] = -2.0f*cx;
      }
      k = r + 1;
      (void)prevm;
    }
    if (lane == 0) sc->nvalid = k;
  }
}

// fused: instance labels + surface-normal heights (4 px/thread, no atomics/barriers)
__global__ __launch_bounds__(256) void k_main(const int* __restrict__ sem, const float* __restrict__ off,
    const float* __restrict__ depth, const float* __restrict__ invK,
    const Scratch* __restrict__ sc, float* __restrict__ out, unsigned* __restrict__ hbuf){
  __shared__ float sck[KC], smy[KC], smx[KC];
  __shared__ int snv;
  int t = threadIdx.x;
  if (t < KC){ sck[t]=sc->ck[t]; smy[t]=sc->m2cy[t]; smx[t]=sc->m2cx[t]; }
  if (t == 0) snv = sc->nvalid;
  __syncthreads();

  int i4 = blockIdx.x*256 + t;
  int p = i4<<2;
  int y = p>>11, x = p&2047;
  int row = y<<11;

  // issue all loads up-front, independent
  int4   s4 = ((const int4*)sem)[i4];
  float4 oy = ((const float4*)off)[i4];
  float4 ox = ((const float4*)(off+HW))[i4];
  float4 dc = ((const float4*)depth)[i4];
  float  dl = depth[row + (x>0 ? x-1 : 0)];
  float  dr = depth[row + (x+4<WW ? x+4 : WW-1)];
  float4 du = ((const float4*)(depth + (y>0     ? row-WW : row)))[x>>2];
  float4 dd = ((const float4*)(depth + (y<HH-1  ? row+WW : row)))[x>>2];

  float ik0=invK[0],ik1=invK[1],ik2=invK[2];
  float ik3=invK[3],ik4=invK[4],ik5=invK[5];
  float ik6=invK[6],ik7=invK[7],ik8=invK[8];

  int   ss[4]  = {s4.x, s4.y, s4.z, s4.w};
  float dcv[4] = {dc.x, dc.y, dc.z, dc.w};
  float duv[4] = {du.x, du.y, du.z, du.w};
  float ddv[4] = {dd.x, dd.y, dd.z, dd.w};
  float oyv[4] = {oy.x, oy.y, oy.z, oy.w};
  float oxv[4] = {ox.x, ox.y, ox.z, ox.w};

  float fy = (float)y;
  // --- instance grouping: d2-argmin via 2fma + sortable-uint min ---
  float ys_[4], xs_[4];
  unsigned ub[4] = {SENT, SENT, SENT, SENT};
  #pragma unroll
  for (int j=0;j<4;j++){ ys_[j] = fy + oyv[j]; xs_[j] = (float)(x+j) + oxv[j]; }
  int nv = snv;
  for (int k=0;k<nv;k++){
    float ckk = sck[k], my = smy[k], mx = smx[k];
    #pragma unroll
    for (int j=0;j<4;j++){
      float tt = fmaf(ys_[j], my, ckk);
      tt = fmaf(xs_[j], mx, tt);
      unsigned u = (__float_as_uint(tt) & ~31u) | (unsigned)k;
      ub[j] = u < ub[j] ? u : ub[j];
    }
  }
  float lab[4];
  #pragma unroll
  for (int j=0;j<4;j++){
    int s = ss[j];
    lab[j] = (s >= 11 && nv > 0) ? (float)(s*1000 + (int)(ub[j]&31u) + 1) : (float)s;
  }
  ((float4*)out)[i4] = make_float4(lab[0], lab[1], lab[2], lab[3]);

  // --- surface-normal heights ---
  float a0 = ik1*fy+ik2, a1 = ik4*fy+ik5, a2 = ik7*fy+ik8;
  float fyu = (y>0)    ? fy-1.0f : fy;
  float fyd = (y<HH-1) ? fy+1.0f : fy;
  float u0 = ik1*fyu+ik2, u1 = ik4*fyu+ik5, u2 = ik7*fyu+ik8;
  float w0 = ik1*fyd+ik2, w1 = ik4*fyd+ik5, w2 = ik7*fyd+ik8;
  float dxmv[4] = {dl, dcv[0], dcv[1], dcv[2]};
  float dxpv[4] = {dcv[1], dcv[2], dcv[3], dr};
  unsigned hk[4];
  #pragma unroll
  for (int j=0;j<4;j++){
    float fx  = (float)(x+j);
    float fxm = (x+j>0)     ? fx-1.0f : fx;
    float fxp = (x+j<WW-1)  ? fx+1.0f : fx;
    float pc0=(ik0*fx +a0)*dcv[j],  pc1=(ik3*fx +a1)*dcv[j],  pc2=(ik6*fx +a2)*dcv[j];
    float pm0=(ik0*fxm+a0)*dxmv[j], pm1=(ik3*fxm+a1)*dxmv[j], pm2=(ik6*fxm+a2)*dxmv[j];
    float pp0=(ik0*fxp+a0)*dxpv[j], pp1=(ik3*fxp+a1)*dxpv[j], pp2=(ik6*fxp+a2)*dxpv[j];
    float pu0=(ik0*fx +u0)*duv[j],  pu1=(ik3*fx +u1)*duv[j],  pu2=(ik6*fx +u2)*duv[j];
    float pd0=(ik0*fx +w0)*ddv[j],  pd1=(ik3*fx +w1)*ddv[j],  pd2=(ik6*fx +w2)*ddv[j];
    float vx0=pp0-pm0, vx1=pp1-pm1, vx2=pp2-pm2;
    float vy0=pd0-pu0, vy1=pd1-pu1, vy2=pd2-pu2;
    float n0=vx1*vy2-vx2*vy1, n1=vx2*vy0-vx0*vy2, n2=vx0*vy1-vx1*vy0;
    float nn = sqrtf(n0*n0+n1*n1+n2*n2) + 1e-8f;
    float h = fabsf(pc0*n0+pc1*n1+pc2*n2) / nn;
    hk[j] = (ss[j]==0) ? __float_as_uint(h) : SENT;
  }
  ((uint4*)hbuf)[i4] = make_uint4(hk[0], hk[1], hk[2], hk[3]);
}

template<int PASS>
__global__ void k_hist(const unsigned* __restrict__ hbuf, Scratch* sc){
  __shared__ unsigned hsh[2048];
  for (int j=threadIdx.x;j<2048;j+=256) hsh[j]=0;
  __syncthreads();
  unsigned pref = sc->prefix;
  for (int i = blockIdx.x*256 + threadIdx.x; i < HW/4; i += gridDim.x*256){
    uint4 kv = ((const uint4*)hbuf)[i];
    unsigned ks[4] = {kv.x, kv.y, kv.z, kv.w};
    #pragma unroll
    for (int j=0;j<4;j++){
      unsigned key = ks[j];
      if (key == SENT) continue;
      if (PASS==0)      atomicAdd(&hsh[key>>21], 1u);
      else if (PASS==1){ if ((key>>21) == pref) atomicAdd(&hsh[(key>>10)&2047u], 1u); }
      else             { if ((key>>10) == pref) atomicAdd(&hsh[key & 1023u], 1u); }
    }
  }
  __syncthreads();
  for (int j=threadIdx.x;j<2048;j+=256){ unsigned v=hsh[j]; if (v) atomicAdd(&sc->hist[j], v); }
}

// parallel k-th-bucket selection: 256 threads x 8 bins, wave scan + LDS scan
template<int PASS>
__global__ void k_pick(Scratch* sc, const float* __restrict__ rch){
  __shared__ unsigned wsum[4];
  int t = threadIdx.x;
  uint4 va = ((const uint4*)sc->hist)[2*t];
  uint4 vb = ((const uint4*)sc->hist)[2*t+1];
  unsigned v[8] = {va.x,va.y,va.z,va.w,vb.x,vb.y,vb.z,vb.w};
  unsigned s = 0;
  #pragma unroll
  for (int j=0;j<8;j++) s += v[j];
  unsigned incl = s;
  #pragma unroll
  for (int d=1; d<64; d<<=1){ unsigned o = __shfl_up(incl, d); if ((t&63) >= d) incl += o; }
  unsigned excl = incl - s;
  if ((t&63)==63) wsum[t>>6] = incl;
  __syncthreads();
  unsigned woff = 0, total = 0;
  #pragma unroll
  for (int w=0;w<4;w++){ unsigned xw = wsum[w]; if (w < (t>>6)) woff += xw; total += xw; }
  unsigned pre = woff + excl;
  int k;
  if (PASS==0){
    int c = (int)total;
    if (t==0) sc->cnt = c;
    k = (c > 0) ? ((c-1)>>1) : 0;
  } else {
    k = sc->kRemain;
  }
  if ((unsigned)k >= pre && (unsigned)k < pre + s){
    unsigned kr = (unsigned)k - pre;
    int b_ = 0;
    #pragma unroll
    for (int j=0;j<8;j++){
      if (kr < v[j]){ b_ = t*8+j; break; }
      kr -= v[j];
    }
    sc->kRemain = (int)kr;
    if (PASS==0)      sc->prefix = (unsigned)b_;
    else if (PASS==1) sc->prefix = (sc->prefix << 11) | (unsigned)b_;
    else {
      unsigned key = (sc->prefix << 10) | (unsigned)b_;
      sc->scale = (sc->cnt > 0) ? (rch[0] / __uint_as_float(key)) : 0.0f;
    }
  }
  __syncthreads();
  ((uint4*)sc->hist)[2*t]   = make_uint4(0,0,0,0);
  ((uint4*)sc->hist)[2*t+1] = make_uint4(0,0,0,0);
}

__global__ __launch_bounds__(256) void k_final(const float* __restrict__ depth, const float* __restrict__ invK,
    const Scratch* __restrict__ sc, float* __restrict__ out){
  int i4 = blockIdx.x*256 + threadIdx.x;
  int p = i4<<2;
  int y = p>>11, x = p&2047;
  float4 l4 = ((const float4*)out)[i4];
  float4 dc = ((const float4*)depth)[i4];
  float s = sc->scale;
  float ik0=invK[0],ik1=invK[1],ik2=invK[2];
  float ik3=invK[3],ik4=invK[4],ik5=invK[5];
  float ik6=invK[6],ik7=invK[7],ik8=invK[8];
  float fy = (float)y;
  float a0 = ik1*fy+ik2, a1 = ik4*fy+ik5, a2 = ik7*fy+ik8;
  float labv[4] = {l4.x, l4.y, l4.z, l4.w};
  float dv[4]   = {dc.x, dc.y, dc.z, dc.w};
  float depo[4];
  float4* cam = (float4*)(out + (size_t)2*HW);
  #pragma unroll
  for (int j=0;j<4;j++){
    float fx = (float)(x+j);
    float ds = dv[j]*s;
    float p0 = (ik0*fx+a0)*ds, p1 = (ik3*fx+a1)*ds, p2 = (ik6*fx+a2)*ds;
    bool filt = (labv[j]==10.0f) || (labv[j]==19.0f);
    depo[j] = filt ? 0.0f : ds;
    cam[p+j] = make_float4(p0, p1, p2, labv[j]);
  }
  ((float4*)(out+HW))[i4] = make_float4(depo[0], depo[1], depo[2], depo[3]);
}

extern "C" void kernel_launch(void* const* d_in, const int* in_sizes, int n_in,
                              void* d_out, int out_size, void* d_ws, size_t ws_size,
                              hipStream_t stream){
  const int*   sem   = (const int*)d_in[0];
  const float* heat  = (const float*)d_in[1];
  const float* off   = (const float*)d_in[2];
  const float* depth = (const float*)d_in[3];
  const float* invK  = (const float*)d_in[4];
  const float* rch   = (const float*)d_in[5];
  float* out = (float*)d_out;

  unsigned* hbuf = (unsigned*)d_ws;                                      // HW*4 bytes
  u64* cand = (u64*)((char*)d_ws + (size_t)HW*4);                        // CAP*8 bytes
  Scratch* sc = (Scratch*)((char*)d_ws + (size_t)HW*4 + (size_t)CAP*8);

  const int blk = 256;
  const int grid4 = HW/4/blk;   // 2048

  hipMemsetAsync(sc, 0, sizeof(Scratch), stream);
  k_collect<<<grid4, blk, 0, stream>>>(heat, cand, sc);
  k_select<<<1, 1024, 0, stream>>>(cand, sc);
  k_main<<<grid4, blk, 0, stream>>>(sem, off, depth, invK, sc, out, hbuf);
  k_hist<0><<<512, blk, 0, stream>>>(hbuf, sc);
  k_pick<0><<<1, blk, 0, stream>>>(sc, rch);
  k_hist<1><<<512, blk, 0, stream>>>(hbuf, sc);
  k_pick<1><<<1, blk, 0, stream>>>(sc, rch);
  k_hist<2><<<512, blk, 0, stream>>>(hbuf, sc);
  k_pick<2><<<1, blk, 0, stream>>>(sc, rch);
  k_final<<<grid4, blk, 0, stream>>>(depth, invK, sc, out);
}